// Round 5
// baseline (484.397 us; speedup 1.0000x reference)
//
#include <hip/hip_runtime.h>
#include <stdint.h>

#define NS 32
#define NIN 2048
#define NOUT 2048

// ================= Threefry-2x32, 4 independent chains, hand-scheduled asm =================
// rot r == v_alignbit_b32(v,v,32-r): shifts 19,17,6,26 / 15,3,16,8 (inline consts).
// NON-volatile: pure function of inputs -> compiler may schedule around it.

#define ADD4                                 \
    "v_add_u32 %[t0], %[t0], %[a0]\n\t"      \
    "v_add_u32 %[t1], %[t1], %[a1]\n\t"      \
    "v_add_u32 %[t2], %[t2], %[a2]\n\t"      \
    "v_add_u32 %[t3], %[t3], %[a3]\n\t"

#define ADDK4                                \
    "v_add_u32 %[t0], %[k0], %[a0]\n\t"      \
    "v_add_u32 %[t1], %[k0], %[a1]\n\t"      \
    "v_add_u32 %[t2], %[k0], %[a2]\n\t"      \
    "v_add_u32 %[t3], %[k0], %[a3]\n\t"

#define ROT4(sh)                                          \
    "v_alignbit_b32 %[a0], %[a0], %[a0], " sh "\n\t"      \
    "v_alignbit_b32 %[a1], %[a1], %[a1], " sh "\n\t"      \
    "v_alignbit_b32 %[a2], %[a2], %[a2], " sh "\n\t"      \
    "v_alignbit_b32 %[a3], %[a3], %[a3], " sh "\n\t"

#define XOR4                                 \
    "v_xor_b32 %[a0], %[a0], %[t0]\n\t"      \
    "v_xor_b32 %[a1], %[a1], %[t1]\n\t"      \
    "v_xor_b32 %[a2], %[a2], %[t2]\n\t"      \
    "v_xor_b32 %[a3], %[a3], %[t3]\n\t"

#define TF4R(sh) ADD4 ROT4(sh) XOR4

#define TF4INJ(ka, kb)                           \
    "v_add_u32 %[t0], %[" ka "], %[t0]\n\t"      \
    "v_add_u32 %[t1], %[" ka "], %[t1]\n\t"      \
    "v_add_u32 %[t2], %[" ka "], %[t2]\n\t"      \
    "v_add_u32 %[t3], %[" ka "], %[t3]\n\t"      \
    "v_add_u32 %[a0], %[" kb "], %[a0]\n\t"      \
    "v_add_u32 %[a1], %[" kb "], %[a1]\n\t"      \
    "v_add_u32 %[a2], %[" kb "], %[a2]\n\t"      \
    "v_add_u32 %[a3], %[" kb "], %[a3]\n\t"

// a_i in: counter+k1.  a_i out: x0^x1 (folded random bits).
__device__ __forceinline__ void tf_fold4(uint32_t k0, uint32_t k1, uint32_t k2,
                                         uint32_t& a0, uint32_t& a1,
                                         uint32_t& a2, uint32_t& a3) {
    uint32_t t0, t1, t2, t3;
    const uint32_t c1 = k2 + 1u, c2 = k0 + 2u, c3 = k1 + 3u, c4 = k2 + 4u, c5 = k0 + 5u;
    asm(ADDK4 ROT4("19") XOR4                       // rounds 1-4 (rot 13,15,26,6)
        TF4R("17") TF4R("6") TF4R("26")
        TF4INJ("k1", "c1")
        TF4R("15") TF4R("3") TF4R("16") TF4R("8")   // rounds 5-8 (rot 17,29,16,24)
        TF4INJ("k2", "c2")
        TF4R("19") TF4R("17") TF4R("6") TF4R("26")  // rounds 9-12
        TF4INJ("k0", "c3")
        TF4R("15") TF4R("3") TF4R("16") TF4R("8")   // rounds 13-16
        TF4INJ("k1", "c4")
        TF4R("19") TF4R("17") TF4R("6") TF4R("26")  // rounds 17-20
        TF4INJ("k2", "c5")
        XOR4                                        // fold x0^x1
        : [a0] "+v"(a0), [a1] "+v"(a1), [a2] "+v"(a2), [a3] "+v"(a3),
          [t0] "=&v"(t0), [t1] "=&v"(t1), [t2] "=&v"(t2), [t3] "=&v"(t3)
        : [k0] "s"(k0), [k1] "s"(k1), [k2] "s"(k2),
          [c1] "s"(c1), [c2] "s"(c2), [c3] "s"(c3), [c4] "s"(c4), [c5] "s"(c5));
}

// ---------- bits -> u in (-1,1) and l2 = log2(1-u^2) ----------
__device__ __forceinline__ void ul2_from_bits(uint32_t bits, float& u, float& l2) {
    const float LO = __uint_as_float(0xBF7FFFFFu);  // nextafter(-1.f, 0.f)
    float f = __uint_as_float((bits >> 9) | 0x3f800000u) - 1.0f;  // [0,1)
    u = fmaf(f, 2.0f, LO);
    l2 = __log2f(fmaf(-u, u, 1.0f));  // raw v_log_f32; ln2 folded into poly arg
}

// sqrt(2)*erfinv poly, sqrt2 folded into coefficients, arg from log2.
// fast: w = -ln2*l2 < 5  <=>  l2 > -7.2134752
__device__ __forceinline__ float erfinv2_fast(float l2) {
    float t = fmaf(l2, -0.69314718f, -2.5f);  // w - 2.5
    float p = 3.9739403e-08f;
    p = fmaf(p, t, 4.8546628e-07f);
    p = fmaf(p, t, -4.9828418e-06f);
    p = fmaf(p, t, -6.2105079e-06f);
    p = fmaf(p, t, 3.0912069e-04f);
    p = fmaf(p, t, -1.7730336e-03f);
    p = fmaf(p, t, -5.9081371e-03f);
    p = fmaf(p, t, 0.34878364f);
    p = fmaf(p, t, 2.1233153f);
    return p;
}

__device__ __forceinline__ float erfinv2_slow(float l2) {
    float w = l2 * -0.69314718f;
    float t = __fsqrt_rn(w) - 3.0f;
    float p = -2.8314685e-04f;
    p = fmaf(p, t, 1.4276577e-04f);
    p = fmaf(p, t, 1.9082652e-03f);
    p = fmaf(p, t, -5.1950077e-03f);
    p = fmaf(p, t, 8.1169428e-03f);
    p = fmaf(p, t, -1.0779843e-02f);
    p = fmaf(p, t, 1.3348618e-02f);
    p = fmaf(p, t, 1.4165813f);
    p = fmaf(p, t, 4.0064342f);
    return p;
}

// scalar threefry fold (bias path; executed once per wave, compiler codegen fine)
__device__ __forceinline__ uint32_t rotl32c(uint32_t v, uint32_t r) {
    return __builtin_amdgcn_alignbit(v, v, 32u - r);
}
#define TF_R1(x0, x1, r) do { x0 += x1; x1 = rotl32c(x1, r) ^ x0; } while (0)
__device__ __forceinline__ uint32_t tf_fold1(uint32_t k0, uint32_t k1, uint32_t k2,
                                             uint32_t x1in) {
    uint32_t x0 = k0 + x1in;
    uint32_t x1 = rotl32c(x1in, 13) ^ x0;
    TF_R1(x0, x1, 15); TF_R1(x0, x1, 26); TF_R1(x0, x1, 6);
    x0 += k1; x1 += k2 + 1u;
    TF_R1(x0, x1, 17); TF_R1(x0, x1, 29); TF_R1(x0, x1, 16); TF_R1(x0, x1, 24);
    x0 += k2; x1 += k0 + 2u;
    TF_R1(x0, x1, 13); TF_R1(x0, x1, 15); TF_R1(x0, x1, 26); TF_R1(x0, x1, 6);
    x0 += k0; x1 += k1 + 3u;
    TF_R1(x0, x1, 17); TF_R1(x0, x1, 29); TF_R1(x0, x1, 16); TF_R1(x0, x1, 24);
    x0 += k1; x1 += k2 + 4u;
    TF_R1(x0, x1, 13); TF_R1(x0, x1, 15); TF_R1(x0, x1, 26); TF_R1(x0, x1, 6);
    x0 += k2; x1 += k0 + 5u;
    return x0 ^ x1;
}

__device__ __forceinline__ float normal_from_bits(uint32_t bits) {
    float u, l2;
    ul2_from_bits(bits, u, l2);
    float p = (l2 > -7.2134752f) ? erfinv2_fast(l2) : erfinv2_slow(l2);
    return p * u;
}

// Block = (o, s-group of 4). Wave w owns s = sg*4+w (wave-uniform -> coalesced x).
// Lane covers i = it*256 + lane*4 + {0..3}; wave reduces full i -> out[s,o].
__global__ __launch_bounds__(256, 6) void bayes_linear_kernel(
    const float* __restrict__ x, const float* __restrict__ wmu,
    const float* __restrict__ wsg, const float* __restrict__ bmu,
    const float* __restrict__ bsg, float* __restrict__ out,
    uint32_t kw0, uint32_t kw1, uint32_t kb0, uint32_t kb1) {
    const uint32_t bid = blockIdx.x;
    const uint32_t o = bid >> 3;
    const uint32_t sg = bid & 7u;
    const uint32_t tid = threadIdx.x;
    const uint32_t wv = tid >> 6;
    const uint32_t lane = tid & 63u;
    const uint32_t s = sg * 4u + wv;

    const uint32_t kw2 = kw0 ^ kw1 ^ 0x1BD11BDAu;
    const uint32_t kb2 = kb0 ^ kb1 ^ 0x1BD11BDAu;

    // threefry counter: s*OUT*IN + o*IN + i, pre-add kw1; lane part folded in
    const uint32_t pbase = s * (uint32_t)(NOUT * NIN) + o * (uint32_t)NIN +
                           kw1 + lane * 4u;

    const float4* __restrict__ mp = (const float4*)(wmu + o * NIN) + lane;
    const float4* __restrict__ gp = (const float4*)(wsg + o * NIN) + lane;
    const float4* __restrict__ xp = (const float4*)(x + s * NIN) + lane;

    float ax = 0.0f, ay = 0.0f, az = 0.0f, aw = 0.0f;
#pragma unroll
    for (int it = 0; it < 8; ++it) {
        const float4 m4 = mp[it * 64];
        const float4 g4 = gp[it * 64];
        const float4 x4 = xp[it * 64];

        const uint32_t p = pbase + (uint32_t)(it * 256);
        uint32_t b0 = p, b1 = p + 1u, b2 = p + 2u, b3 = p + 3u;
        tf_fold4(kw0, kw1, kw2, b0, b1, b2, b3);

        float u0, u1, u2, u3, l0, l1, l2v, l3;
        ul2_from_bits(b0, u0, l0);
        ul2_from_bits(b1, u1, l1);
        ul2_from_bits(b2, u2, l2v);
        ul2_from_bits(b3, u3, l3);
        float p0 = erfinv2_fast(l0);
        float p1 = erfinv2_fast(l1);
        float p2 = erfinv2_fast(l2v);
        float p3 = erfinv2_fast(l3);
        // slow tail (~0.3% of lanes): whole block skipped by ~96% of waves
        if (__any(fminf(fminf(l0, l1), fminf(l2v, l3)) <= -7.2134752f)) {
            if (l0 <= -7.2134752f) p0 = erfinv2_slow(l0);
            if (l1 <= -7.2134752f) p1 = erfinv2_slow(l1);
            if (l2v <= -7.2134752f) p2 = erfinv2_slow(l2v);
            if (l3 <= -7.2134752f) p3 = erfinv2_slow(l3);
        }
        const float e0 = p0 * u0;
        const float e1 = p1 * u1;
        const float e2 = p2 * u2;
        const float e3 = p3 * u3;

        ax = fmaf(fmaf(g4.x, e0, m4.x), x4.x, ax);
        ay = fmaf(fmaf(g4.y, e1, m4.y), x4.y, ay);
        az = fmaf(fmaf(g4.z, e2, m4.z), x4.z, az);
        aw = fmaf(fmaf(g4.w, e3, m4.w), x4.w, aw);
    }

    float v = (ax + ay) + (az + aw);
    v += __shfl_down(v, 32, 64);
    v += __shfl_down(v, 16, 64);
    v += __shfl_down(v, 8, 64);
    v += __shfl_down(v, 4, 64);
    v += __shfl_down(v, 2, 64);
    v += __shfl_down(v, 1, 64);

    if (lane == 0) {
        const uint32_t pb = s * (uint32_t)NOUT + o + kb1;
        const float eb = normal_from_bits(tf_fold1(kb0, kb1, kb2, pb));
        out[s * NOUT + o] = v + fmaf(bsg[o], eb, bmu[o]);
    }
}

// ---------- host-side threefry for key derivation ----------
#define TF_ROUND_H(x0, x1, r)                     \
    do {                                          \
        x0 += x1;                                 \
        x1 = (x1 << (r)) | (x1 >> (32 - (r)));    \
        x1 ^= x0;                                 \
    } while (0)

static void tf2x32_host(uint32_t k0, uint32_t k1, uint32_t x0, uint32_t x1,
                        uint32_t* y0, uint32_t* y1) {
    uint32_t k2 = k0 ^ k1 ^ 0x1BD11BDAu;
    x0 += k0; x1 += k1;
    TF_ROUND_H(x0, x1, 13); TF_ROUND_H(x0, x1, 15); TF_ROUND_H(x0, x1, 26); TF_ROUND_H(x0, x1, 6);
    x0 += k1; x1 += k2 + 1u;
    TF_ROUND_H(x0, x1, 17); TF_ROUND_H(x0, x1, 29); TF_ROUND_H(x0, x1, 16); TF_ROUND_H(x0, x1, 24);
    x0 += k2; x1 += k0 + 2u;
    TF_ROUND_H(x0, x1, 13); TF_ROUND_H(x0, x1, 15); TF_ROUND_H(x0, x1, 26); TF_ROUND_H(x0, x1, 6);
    x0 += k0; x1 += k1 + 3u;
    TF_ROUND_H(x0, x1, 17); TF_ROUND_H(x0, x1, 29); TF_ROUND_H(x0, x1, 16); TF_ROUND_H(x0, x1, 24);
    x0 += k1; x1 += k2 + 4u;
    TF_ROUND_H(x0, x1, 13); TF_ROUND_H(x0, x1, 15); TF_ROUND_H(x0, x1, 26); TF_ROUND_H(x0, x1, 6);
    x0 += k2; x1 += k0 + 5u;
    *y0 = x0; *y1 = x1;
}

extern "C" void kernel_launch(void* const* d_in, const int* in_sizes, int n_in,
                              void* d_out, int out_size, void* d_ws, size_t ws_size,
                              hipStream_t stream) {
    const float* x   = (const float*)d_in[0];
    const float* wmu = (const float*)d_in[1];
    const float* wsg = (const float*)d_in[2];
    const float* bmu = (const float*)d_in[3];
    const float* bsg = (const float*)d_in[4];
    float* out = (float*)d_out;

    uint32_t kw0, kw1, kb0, kb1;
    tf2x32_host(0u, 42u, 0u, 0u, &kw0, &kw1);  // wkey = split(key(42))[0]
    tf2x32_host(0u, 42u, 0u, 1u, &kb0, &kb1);  // bkey = split(key(42))[1]

    bayes_linear_kernel<<<NOUT * 8, 256, 0, stream>>>(x, wmu, wsg, bmu, bsg, out,
                                                      kw0, kw1, kb0, kb1);
}

// Round 6
// 321.584 us; speedup vs baseline: 1.5063x; 1.5063x over previous
//
#include <hip/hip_runtime.h>
#include <stdint.h>

#define NS 32
#define NIN 2048
#define NOUT 2048

// ================= Threefry-2x32, 4 independent chains, hand-scheduled asm =================
// rot r == v_alignbit_b32(v,v,32-r): shifts 19,17,6,26 / 15,3,16,8 (inline consts).
// NON-volatile pure asm: compiler may schedule loads around it. Validated bit-exact (R4/R5).

#define ADD4                                 \
    "v_add_u32 %[t0], %[t0], %[a0]\n\t"      \
    "v_add_u32 %[t1], %[t1], %[a1]\n\t"      \
    "v_add_u32 %[t2], %[t2], %[a2]\n\t"      \
    "v_add_u32 %[t3], %[t3], %[a3]\n\t"

#define ADDK4                                \
    "v_add_u32 %[t0], %[k0], %[a0]\n\t"      \
    "v_add_u32 %[t1], %[k0], %[a1]\n\t"      \
    "v_add_u32 %[t2], %[k0], %[a2]\n\t"      \
    "v_add_u32 %[t3], %[k0], %[a3]\n\t"

#define ROT4(sh)                                          \
    "v_alignbit_b32 %[a0], %[a0], %[a0], " sh "\n\t"      \
    "v_alignbit_b32 %[a1], %[a1], %[a1], " sh "\n\t"      \
    "v_alignbit_b32 %[a2], %[a2], %[a2], " sh "\n\t"      \
    "v_alignbit_b32 %[a3], %[a3], %[a3], " sh "\n\t"

#define XOR4                                 \
    "v_xor_b32 %[a0], %[a0], %[t0]\n\t"      \
    "v_xor_b32 %[a1], %[a1], %[t1]\n\t"      \
    "v_xor_b32 %[a2], %[a2], %[t2]\n\t"      \
    "v_xor_b32 %[a3], %[a3], %[t3]\n\t"

#define TF4R(sh) ADD4 ROT4(sh) XOR4

#define TF4INJ(ka, kb)                           \
    "v_add_u32 %[t0], %[" ka "], %[t0]\n\t"      \
    "v_add_u32 %[t1], %[" ka "], %[t1]\n\t"      \
    "v_add_u32 %[t2], %[" ka "], %[t2]\n\t"      \
    "v_add_u32 %[t3], %[" ka "], %[t3]\n\t"      \
    "v_add_u32 %[a0], %[" kb "], %[a0]\n\t"      \
    "v_add_u32 %[a1], %[" kb "], %[a1]\n\t"      \
    "v_add_u32 %[a2], %[" kb "], %[a2]\n\t"      \
    "v_add_u32 %[a3], %[" kb "], %[a3]\n\t"

// a_i in: counter+k1.  a_i out: x0^x1 (folded random bits).
__device__ __forceinline__ void tf_fold4(uint32_t k0, uint32_t k1, uint32_t k2,
                                         uint32_t& a0, uint32_t& a1,
                                         uint32_t& a2, uint32_t& a3) {
    uint32_t t0, t1, t2, t3;
    const uint32_t c1 = k2 + 1u, c2 = k0 + 2u, c3 = k1 + 3u, c4 = k2 + 4u, c5 = k0 + 5u;
    asm(ADDK4 ROT4("19") XOR4                       // rounds 1-4 (rot 13,15,26,6)
        TF4R("17") TF4R("6") TF4R("26")
        TF4INJ("k1", "c1")
        TF4R("15") TF4R("3") TF4R("16") TF4R("8")   // rounds 5-8 (rot 17,29,16,24)
        TF4INJ("k2", "c2")
        TF4R("19") TF4R("17") TF4R("6") TF4R("26")  // rounds 9-12
        TF4INJ("k0", "c3")
        TF4R("15") TF4R("3") TF4R("16") TF4R("8")   // rounds 13-16
        TF4INJ("k1", "c4")
        TF4R("19") TF4R("17") TF4R("6") TF4R("26")  // rounds 17-20
        TF4INJ("k2", "c5")
        XOR4                                        // fold x0^x1
        : [a0] "+v"(a0), [a1] "+v"(a1), [a2] "+v"(a2), [a3] "+v"(a3),
          [t0] "=&v"(t0), [t1] "=&v"(t1), [t2] "=&v"(t2), [t3] "=&v"(t3)
        : [k0] "s"(k0), [k1] "s"(k1), [k2] "s"(k2),
          [c1] "s"(c1), [c2] "s"(c2), [c3] "s"(c3), [c4] "s"(c4), [c5] "s"(c5));
}

// ---------- bits -> u in (-1,1) and l2 = log2(1-u^2) ----------
__device__ __forceinline__ void ul2_from_bits(uint32_t bits, float& u, float& l2) {
    const float LO = __uint_as_float(0xBF7FFFFFu);  // nextafter(-1.f, 0.f)
    float f = __uint_as_float((bits >> 9) | 0x3f800000u) - 1.0f;  // [0,1)
    u = fmaf(f, 2.0f, LO);
    l2 = __log2f(fmaf(-u, u, 1.0f));  // raw v_log_f32; ln2 folded into poly arg
}

// sqrt(2)*erfinv poly, sqrt2 folded into coefficients, arg from log2 (validated R5).
// fast branch iff l2 > -7.2134752  (w = -ln2*l2 < 5)
__device__ __forceinline__ float erfinv2_fast(float l2) {
    float t = fmaf(l2, -0.69314718f, -2.5f);  // w - 2.5
    float p = 3.9739403e-08f;
    p = fmaf(p, t, 4.8546628e-07f);
    p = fmaf(p, t, -4.9828418e-06f);
    p = fmaf(p, t, -6.2105079e-06f);
    p = fmaf(p, t, 3.0912069e-04f);
    p = fmaf(p, t, -1.7730336e-03f);
    p = fmaf(p, t, -5.9081371e-03f);
    p = fmaf(p, t, 0.34878364f);
    p = fmaf(p, t, 2.1233153f);
    return p;
}

__device__ __forceinline__ float erfinv2_slow(float l2) {
    float w = l2 * -0.69314718f;
    float t = __fsqrt_rn(w) - 3.0f;
    float p = -2.8314685e-04f;
    p = fmaf(p, t, 1.4276577e-04f);
    p = fmaf(p, t, 1.9082652e-03f);
    p = fmaf(p, t, -5.1950077e-03f);
    p = fmaf(p, t, 8.1169428e-03f);
    p = fmaf(p, t, -1.0779843e-02f);
    p = fmaf(p, t, 1.3348618e-02f);
    p = fmaf(p, t, 1.4165813f);
    p = fmaf(p, t, 4.0064342f);
    return p;
}

// scalar threefry fold (bias path)
__device__ __forceinline__ uint32_t rotl32c(uint32_t v, uint32_t r) {
    return __builtin_amdgcn_alignbit(v, v, 32u - r);
}
#define TF_R1(x0, x1, r) do { x0 += x1; x1 = rotl32c(x1, r) ^ x0; } while (0)
__device__ __forceinline__ uint32_t tf_fold1(uint32_t k0, uint32_t k1, uint32_t k2,
                                             uint32_t x1in) {
    uint32_t x0 = k0 + x1in;
    uint32_t x1 = rotl32c(x1in, 13) ^ x0;
    TF_R1(x0, x1, 15); TF_R1(x0, x1, 26); TF_R1(x0, x1, 6);
    x0 += k1; x1 += k2 + 1u;
    TF_R1(x0, x1, 17); TF_R1(x0, x1, 29); TF_R1(x0, x1, 16); TF_R1(x0, x1, 24);
    x0 += k2; x1 += k0 + 2u;
    TF_R1(x0, x1, 13); TF_R1(x0, x1, 15); TF_R1(x0, x1, 26); TF_R1(x0, x1, 6);
    x0 += k0; x1 += k1 + 3u;
    TF_R1(x0, x1, 17); TF_R1(x0, x1, 29); TF_R1(x0, x1, 16); TF_R1(x0, x1, 24);
    x0 += k1; x1 += k2 + 4u;
    TF_R1(x0, x1, 13); TF_R1(x0, x1, 15); TF_R1(x0, x1, 26); TF_R1(x0, x1, 6);
    x0 += k2; x1 += k0 + 5u;
    return x0 ^ x1;
}

__device__ __forceinline__ float normal_from_bits(uint32_t bits) {
    float u, l2;
    ul2_from_bits(bits, u, l2);
    float p = (l2 > -7.2134752f) ? erfinv2_fast(l2) : erfinv2_slow(l2);
    return p * u;
}

// 4 eps tail: bits b0..b3 -> e0..e3
#define TAIL4(B0, B1, B2, B3, E0, E1, E2, E3)                                   \
    {                                                                           \
        float u0, u1, u2, u3, l0, l1, l2v, l3;                                  \
        ul2_from_bits(B0, u0, l0);                                              \
        ul2_from_bits(B1, u1, l1);                                              \
        ul2_from_bits(B2, u2, l2v);                                             \
        ul2_from_bits(B3, u3, l3);                                              \
        float q0 = erfinv2_fast(l0);                                            \
        float q1 = erfinv2_fast(l1);                                            \
        float q2 = erfinv2_fast(l2v);                                           \
        float q3 = erfinv2_fast(l3);                                            \
        if (__any(fminf(fminf(l0, l1), fminf(l2v, l3)) <= -7.2134752f)) {       \
            if (l0 <= -7.2134752f) q0 = erfinv2_slow(l0);                       \
            if (l1 <= -7.2134752f) q1 = erfinv2_slow(l1);                       \
            if (l2v <= -7.2134752f) q2 = erfinv2_slow(l2v);                     \
            if (l3 <= -7.2134752f) q3 = erfinv2_slow(l3);                       \
        }                                                                       \
        E0 = q0 * u0;                                                           \
        E1 = q1 * u1;                                                           \
        E2 = q2 * u2;                                                           \
        E3 = q3 * u3;                                                           \
    }

// Block = o (row read once, coalesced). Wave w owns s in [8w, 8w+8) (wave-uniform
// via readfirstlane -> SGPR x-row bases). Lane spans i. Per j-iter: 2x tf_fold4
// (chains differ in s by 2^22), 8 eps, 8 FMAs. No LDS, no barrier.
__global__ __launch_bounds__(256) void bayes_linear_kernel(
    const float* __restrict__ x, const float* __restrict__ wmu,
    const float* __restrict__ wsg, const float* __restrict__ bmu,
    const float* __restrict__ bsg, float* __restrict__ out,
    uint32_t kw0, uint32_t kw1, uint32_t kb0, uint32_t kb1) {
    const uint32_t o = blockIdx.x;
    const uint32_t tid = threadIdx.x;
    const uint32_t lane = tid & 63u;
    const uint32_t wv = (uint32_t)__builtin_amdgcn_readfirstlane((int)(tid >> 6));
    const uint32_t sb = wv * 8u;  // wave-uniform first s

    const uint32_t kw2 = kw0 ^ kw1 ^ 0x1BD11BDAu;
    const uint32_t kb2 = kb0 ^ kb1 ^ 0x1BD11BDAu;

    const float* __restrict__ mrow = wmu + o * NIN;
    const float* __restrict__ grow = wsg + o * NIN;
    const float* __restrict__ xr0 = x + (sb + 0u) * NIN;
    const float* __restrict__ xr1 = x + (sb + 1u) * NIN;
    const float* __restrict__ xr2 = x + (sb + 2u) * NIN;
    const float* __restrict__ xr3 = x + (sb + 3u) * NIN;
    const float* __restrict__ xr4 = x + (sb + 4u) * NIN;
    const float* __restrict__ xr5 = x + (sb + 5u) * NIN;
    const float* __restrict__ xr6 = x + (sb + 6u) * NIN;
    const float* __restrict__ xr7 = x + (sb + 7u) * NIN;

    // weight counter: p = s*2^22 + o*2^11 + i (+k1 pre-added)
    const uint32_t pw = (sb << 22) + (o << 11) + kw1;

    float a0 = 0.f, a1 = 0.f, a2 = 0.f, a3 = 0.f;
    float a4 = 0.f, a5 = 0.f, a6 = 0.f, a7 = 0.f;

#pragma unroll 1
    for (uint32_t j = 0; j < NIN; j += 64u) {
        const uint32_t i = j + lane;
        const float mu = mrow[i];
        const float sg = grow[i];
        const float x0v = xr0[i];
        const float x1v = xr1[i];
        const float x2v = xr2[i];
        const float x3v = xr3[i];
        const float x4v = xr4[i];
        const float x5v = xr5[i];
        const float x6v = xr6[i];
        const float x7v = xr7[i];
        const uint32_t pb = pw + i;

        uint32_t b0 = pb, b1 = pb + (1u << 22), b2 = pb + (2u << 22), b3 = pb + (3u << 22);
        tf_fold4(kw0, kw1, kw2, b0, b1, b2, b3);
        float e0, e1, e2, e3;
        TAIL4(b0, b1, b2, b3, e0, e1, e2, e3);
        a0 = fmaf(fmaf(sg, e0, mu), x0v, a0);
        a1 = fmaf(fmaf(sg, e1, mu), x1v, a1);
        a2 = fmaf(fmaf(sg, e2, mu), x2v, a2);
        a3 = fmaf(fmaf(sg, e3, mu), x3v, a3);

        uint32_t c0 = pb + (4u << 22), c1 = pb + (5u << 22), c2 = pb + (6u << 22), c3 = pb + (7u << 22);
        tf_fold4(kw0, kw1, kw2, c0, c1, c2, c3);
        float e4, e5, e6, e7;
        TAIL4(c0, c1, c2, c3, e4, e5, e6, e7);
        a4 = fmaf(fmaf(sg, e4, mu), x4v, a4);
        a5 = fmaf(fmaf(sg, e5, mu), x5v, a5);
        a6 = fmaf(fmaf(sg, e6, mu), x6v, a6);
        a7 = fmaf(fmaf(sg, e7, mu), x7v, a7);
    }

    // butterfly all-reduce each accumulator across the wave
#define RED(v)                          \
    v += __shfl_xor(v, 32, 64);         \
    v += __shfl_xor(v, 16, 64);         \
    v += __shfl_xor(v, 8, 64);          \
    v += __shfl_xor(v, 4, 64);          \
    v += __shfl_xor(v, 2, 64);          \
    v += __shfl_xor(v, 1, 64);
    RED(a0) RED(a1) RED(a2) RED(a3) RED(a4) RED(a5) RED(a6) RED(a7)
#undef RED

    if (lane < 8u) {
        float mysum = a0;
        mysum = (lane == 1u) ? a1 : mysum;
        mysum = (lane == 2u) ? a2 : mysum;
        mysum = (lane == 3u) ? a3 : mysum;
        mysum = (lane == 4u) ? a4 : mysum;
        mysum = (lane == 5u) ? a5 : mysum;
        mysum = (lane == 6u) ? a6 : mysum;
        mysum = (lane == 7u) ? a7 : mysum;
        const uint32_t s = sb + lane;
        const uint32_t pbb = s * (uint32_t)NOUT + o + kb1;  // eps_b index: s*OUT + o
        const float eb = normal_from_bits(tf_fold1(kb0, kb1, kb2, pbb));
        out[s * NOUT + o] = mysum + fmaf(bsg[o], eb, bmu[o]);
    }
}

// ---------- host-side threefry for key derivation ----------
#define TF_ROUND_H(x0, x1, r)                     \
    do {                                          \
        x0 += x1;                                 \
        x1 = (x1 << (r)) | (x1 >> (32 - (r)));    \
        x1 ^= x0;                                 \
    } while (0)

static void tf2x32_host(uint32_t k0, uint32_t k1, uint32_t x0, uint32_t x1,
                        uint32_t* y0, uint32_t* y1) {
    uint32_t k2 = k0 ^ k1 ^ 0x1BD11BDAu;
    x0 += k0; x1 += k1;
    TF_ROUND_H(x0, x1, 13); TF_ROUND_H(x0, x1, 15); TF_ROUND_H(x0, x1, 26); TF_ROUND_H(x0, x1, 6);
    x0 += k1; x1 += k2 + 1u;
    TF_ROUND_H(x0, x1, 17); TF_ROUND_H(x0, x1, 29); TF_ROUND_H(x0, x1, 16); TF_ROUND_H(x0, x1, 24);
    x0 += k2; x1 += k0 + 2u;
    TF_ROUND_H(x0, x1, 13); TF_ROUND_H(x0, x1, 15); TF_ROUND_H(x0, x1, 26); TF_ROUND_H(x0, x1, 6);
    x0 += k0; x1 += k1 + 3u;
    TF_ROUND_H(x0, x1, 17); TF_ROUND_H(x0, x1, 29); TF_ROUND_H(x0, x1, 16); TF_ROUND_H(x0, x1, 24);
    x0 += k1; x1 += k2 + 4u;
    TF_ROUND_H(x0, x1, 13); TF_ROUND_H(x0, x1, 15); TF_ROUND_H(x0, x1, 26); TF_ROUND_H(x0, x1, 6);
    x0 += k2; x1 += k0 + 5u;
    *y0 = x0; *y1 = x1;
}

extern "C" void kernel_launch(void* const* d_in, const int* in_sizes, int n_in,
                              void* d_out, int out_size, void* d_ws, size_t ws_size,
                              hipStream_t stream) {
    const float* x   = (const float*)d_in[0];
    const float* wmu = (const float*)d_in[1];
    const float* wsg = (const float*)d_in[2];
    const float* bmu = (const float*)d_in[3];
    const float* bsg = (const float*)d_in[4];
    float* out = (float*)d_out;

    uint32_t kw0, kw1, kb0, kb1;
    tf2x32_host(0u, 42u, 0u, 0u, &kw0, &kw1);  // wkey = split(key(42))[0]
    tf2x32_host(0u, 42u, 0u, 1u, &kb0, &kb1);  // bkey = split(key(42))[1]

    bayes_linear_kernel<<<NOUT, 256, 0, stream>>>(x, wmu, wsg, bmu, bsg, out,
                                                  kw0, kw1, kb0, kb1);
}